// Round 4
// baseline (203.950 us; speedup 1.0000x reference)
//
#include <hip/hip_runtime.h>

constexpr int F = 2048;            // NUM_FEATURES
constexpr int NROWS = 8192;        // rows
constexpr float EPS = 1e-6f;
constexpr int S4 = F / 4;          // 512 float4 per row

// ---- reduce grid: 8 colgroups x 256 rowgroups = 2048 blocks ----
constexpr int CG = 8;
constexpr int RG = 256;
constexpr int NB1 = CG * RG;
constexpr int RPT = 8;             // rows per thread (32 rows/block over 4 subgroups)

// ws layout (bytes): [0,16384) acc (sum[F], sumsq[F]) | [16384,16448) done ctr
//                    [16448, ...) stats (r[F], b[F])
// memset zeroes acc + done each call.

__global__ __launch_bounds__(256) void reduce_kernel(const float* __restrict__ x,
                                                     float* __restrict__ acc,
                                                     float* __restrict__ stats,
                                                     unsigned* __restrict__ done) {
    __shared__ float4 lS[3 * 64];
    __shared__ float4 lQ[3 * 64];
    __shared__ unsigned lastFlag;

    const int tid = threadIdx.x;
    const int lc  = tid & 63;
    const int sg  = tid >> 6;
    const int cg  = blockIdx.x & (CG - 1);
    const int rg  = blockIdx.x >> 3;
    const int c4  = cg * 64 + lc;
    const int row0 = rg * 32 + sg * RPT;

    const float4* __restrict__ xv = reinterpret_cast<const float4*>(x);

    float4 s = make_float4(0.f, 0.f, 0.f, 0.f);
    float4 q = make_float4(0.f, 0.f, 0.f, 0.f);
    const size_t base = (size_t)row0 * S4 + (size_t)c4;
#pragma unroll
    for (int r = 0; r < RPT; ++r) {
        float4 v = xv[base + (size_t)r * S4];
        s.x += v.x;  s.y += v.y;  s.z += v.z;  s.w += v.w;
        q.x += v.x * v.x;  q.y += v.y * v.y;
        q.z += v.z * v.z;  q.w += v.w * v.w;
    }

    if (sg != 0) {
        lS[(sg - 1) * 64 + lc] = s;
        lQ[(sg - 1) * 64 + lc] = q;
    }
    __syncthreads();
    if (sg == 0) {
#pragma unroll
        for (int k = 0; k < 3; ++k) {
            float4 t = lS[k * 64 + lc];
            float4 u = lQ[k * 64 + lc];
            s.x += t.x;  s.y += t.y;  s.z += t.z;  s.w += t.w;
            q.x += u.x;  q.y += u.y;  q.z += u.z;  q.w += u.w;
        }
        const int c = c4 * 4;
        atomicAdd(&acc[c + 0], s.x);
        atomicAdd(&acc[c + 1], s.y);
        atomicAdd(&acc[c + 2], s.z);
        atomicAdd(&acc[c + 3], s.w);
        atomicAdd(&acc[F + c + 0], q.x);
        atomicAdd(&acc[F + c + 1], q.y);
        atomicAdd(&acc[F + c + 2], q.z);
        atomicAdd(&acc[F + c + 3], q.w);
    }

    // ---- last-block-done: only the final block computes stats (no spinning) ----
    __syncthreads();                       // drains vmcnt: this block's atomics issued
    if (tid == 0) {
        __threadfence();                   // release our atomics
        unsigned old = atomicAdd(done, 1u);
        lastFlag = (old == (unsigned)(NB1 - 1)) ? 1u : 0u;
    }
    __syncthreads();
    if (lastFlag) {
        // agent-scope acquire loads: read coherent accumulator values
#pragma unroll
        for (int k = 0; k < F / 256; ++k) {
            const int c = tid + k * 256;   // coalesced
            const float s1 = __hip_atomic_load(&acc[c],     __ATOMIC_ACQUIRE, __HIP_MEMORY_SCOPE_AGENT);
            const float s2 = __hip_atomic_load(&acc[c + F], __ATOMIC_ACQUIRE, __HIP_MEMORY_SCOPE_AGENT);
            const float mean = s1 * (1.0f / (float)NROWS);
            float var = (s2 - s1 * mean) * (1.0f / (float)(NROWS - 1));
            var = fmaxf(var, 0.0f);
            const float r = rsqrtf(var + EPS);
            stats[c]     = r;
            stats[c + F] = -mean * r;      // out = x*r + b
        }
    }
}

// ---- normalize: 8 float4 per thread; chunk stride is a multiple of the row
//      length, so all 8 elements share one column index -> stats loaded once ----
constexpr int NPT = 8;
constexpr int TOTAL4 = NROWS * S4;        // 4,194,304
constexpr int CHUNK = TOTAL4 / NPT;       // 524,288 (multiple of S4=512)

__global__ __launch_bounds__(256) void normalize_kernel(const float* __restrict__ x,
                                                        const float* __restrict__ stats,
                                                        float* __restrict__ out) {
    const int i = blockIdx.x * 256 + threadIdx.x;        // 0 .. CHUNK-1
    const int c4 = i & (S4 - 1);
    const float4* __restrict__ xv = reinterpret_cast<const float4*>(x);
    float4* __restrict__ ov       = reinterpret_cast<float4*>(out);
    const float4 r = reinterpret_cast<const float4*>(stats)[c4];
    const float4 b = reinterpret_cast<const float4*>(stats + F)[c4];

    float4 v[NPT];
#pragma unroll
    for (int k = 0; k < NPT; ++k) {
        v[k] = xv[(size_t)i + (size_t)k * CHUNK];
    }
#pragma unroll
    for (int k = 0; k < NPT; ++k) {
        float4 o;
        o.x = fmaf(v[k].x, r.x, b.x);
        o.y = fmaf(v[k].y, r.y, b.y);
        o.z = fmaf(v[k].z, r.z, b.z);
        o.w = fmaf(v[k].w, r.w, b.w);
        ov[(size_t)i + (size_t)k * CHUNK] = o;
    }
}

extern "C" void kernel_launch(void* const* d_in, const int* in_sizes, int n_in,
                              void* d_out, int out_size, void* d_ws, size_t ws_size,
                              hipStream_t stream) {
    const float* x = (const float*)d_in[0];
    // running_mean / running_var are wiped by the Welford recurrence (n=1 / n=2).
    float* out    = (float*)d_out;
    float* acc    = (float*)d_ws;                                // 2F floats
    unsigned* done = (unsigned*)((char*)d_ws + 2 * F * sizeof(float));
    float* stats  = (float*)((char*)d_ws + 2 * F * sizeof(float) + 64);

    // zero acc + done counter (ws is re-poisoned 0xAA before every call)
    hipMemsetAsync(d_ws, 0, 2 * F * sizeof(float) + 64, stream);

    reduce_kernel<<<NB1, 256, 0, stream>>>(x, acc, stats, done);
    normalize_kernel<<<CHUNK / 256, 256, 0, stream>>>(x, stats, out);
}

// Round 5
// 139.458 us; speedup vs baseline: 1.4625x; 1.4625x over previous
//
#include <hip/hip_runtime.h>

constexpr int F = 2048;            // NUM_FEATURES
constexpr int NROWS = 8192;        // rows
constexpr float EPS = 1e-6f;
constexpr int S4 = F / 4;          // 512 float4 per row

// ---- Stage A grid: 8 colgroups x 128 rowgroups = 1024 blocks (4/CU) ----
constexpr int CG = 8;
constexpr int RG = 128;
constexpr int NB1 = CG * RG;
constexpr int RPT = 16;            // rows per thread; block covers 64 rows x 64 float4-cols

// ws layout (no zero-init needed -- every byte read later is written first):
//   pS: RG*S4 float4  (partial sums)    [2 MB total with pQ]
//   pQ: RG*S4 float4  (partial sumsq)
//   stats: 2F floats  (rstd, -mean*rstd)

using fx4 = __attribute__((ext_vector_type(4))) float;

// ---------------------------------------------------------------------------
// Stage A: per-block partial sum/sumsq -> plain float4 stores (NO atomics).
// ---------------------------------------------------------------------------
__global__ __launch_bounds__(256) void partial_kernel(const float* __restrict__ x,
                                                      float4* __restrict__ pS,
                                                      float4* __restrict__ pQ) {
    __shared__ float4 lS[3 * 64];
    __shared__ float4 lQ[3 * 64];

    const int tid = threadIdx.x;
    const int lc  = tid & 63;
    const int sg  = tid >> 6;
    const int cg  = blockIdx.x & (CG - 1);
    const int rg  = blockIdx.x >> 3;
    const int c4  = cg * 64 + lc;
    const int row0 = rg * 64 + sg * RPT;

    const float4* __restrict__ xv = reinterpret_cast<const float4*>(x);

    float4 s = make_float4(0.f, 0.f, 0.f, 0.f);
    float4 q = make_float4(0.f, 0.f, 0.f, 0.f);
    const size_t base = (size_t)row0 * S4 + (size_t)c4;
#pragma unroll
    for (int r = 0; r < RPT; ++r) {
        float4 v = xv[base + (size_t)r * S4];
        s.x += v.x;  s.y += v.y;  s.z += v.z;  s.w += v.w;
        q.x += v.x * v.x;  q.y += v.y * v.y;
        q.z += v.z * v.z;  q.w += v.w * v.w;
    }

    if (sg != 0) {
        lS[(sg - 1) * 64 + lc] = s;
        lQ[(sg - 1) * 64 + lc] = q;
    }
    __syncthreads();
    if (sg == 0) {
#pragma unroll
        for (int k = 0; k < 3; ++k) {
            float4 t = lS[k * 64 + lc];
            float4 u = lQ[k * 64 + lc];
            s.x += t.x;  s.y += t.y;  s.z += t.z;  s.w += t.w;
            q.x += u.x;  q.y += u.y;  q.z += u.z;  q.w += u.w;
        }
        pS[(size_t)rg * S4 + c4] = s;   // plain stores -- no atomics, no fence
        pQ[(size_t)rg * S4 + c4] = q;
    }
}

// ---------------------------------------------------------------------------
// Stage B: sum 128 partials per scalar column, emit (rstd, -mean*rstd).
// 8 blocks x 256 threads; partials are L2-resident (2 MB). Coalesced.
// ---------------------------------------------------------------------------
__global__ __launch_bounds__(256) void stats_kernel(const float* __restrict__ pS,
                                                    const float* __restrict__ pQ,
                                                    float* __restrict__ stats) {
    const int c = blockIdx.x * 256 + threadIdx.x;   // 0..F-1
    float s1 = 0.f, s2 = 0.f;
#pragma unroll 8
    for (int b = 0; b < RG; ++b) {
        s1 += pS[(size_t)b * F + c];
        s2 += pQ[(size_t)b * F + c];
    }
    const float mean = s1 * (1.0f / (float)NROWS);
    float var = (s2 - s1 * mean) * (1.0f / (float)(NROWS - 1));
    var = fmaxf(var, 0.0f);
    const float r = rsqrtf(var + EPS);
    stats[c]     = r;
    stats[c + F] = -mean * r;           // out = x*r + b
}

// ---------------------------------------------------------------------------
// Stage C: normalize. 8 float4/thread, one stats load (chunk stride is a
// multiple of the row length). Non-temporal stores keep x resident in L3.
// ---------------------------------------------------------------------------
constexpr int NPT = 8;
constexpr int TOTAL4 = NROWS * S4;        // 4,194,304
constexpr int CHUNK = TOTAL4 / NPT;       // 524,288 (multiple of S4)

__global__ __launch_bounds__(256) void normalize_kernel(const float* __restrict__ x,
                                                        const float* __restrict__ stats,
                                                        float* __restrict__ out) {
    const int i = blockIdx.x * 256 + threadIdx.x;    // 0 .. CHUNK-1
    const int c4 = i & (S4 - 1);
    const float4* __restrict__ xv = reinterpret_cast<const float4*>(x);
    fx4* __restrict__ ov          = reinterpret_cast<fx4*>(out);
    const float4 r = reinterpret_cast<const float4*>(stats)[c4];
    const float4 b = reinterpret_cast<const float4*>(stats + F)[c4];

    float4 v[NPT];
#pragma unroll
    for (int k = 0; k < NPT; ++k) {
        v[k] = xv[(size_t)i + (size_t)k * CHUNK];
    }
#pragma unroll
    for (int k = 0; k < NPT; ++k) {
        fx4 o;
        o.x = fmaf(v[k].x, r.x, b.x);
        o.y = fmaf(v[k].y, r.y, b.y);
        o.z = fmaf(v[k].z, r.z, b.z);
        o.w = fmaf(v[k].w, r.w, b.w);
        __builtin_nontemporal_store(o, &ov[(size_t)i + (size_t)k * CHUNK]);
    }
}

extern "C" void kernel_launch(void* const* d_in, const int* in_sizes, int n_in,
                              void* d_out, int out_size, void* d_ws, size_t ws_size,
                              hipStream_t stream) {
    const float* x = (const float*)d_in[0];
    // running_mean / running_var are wiped by the Welford recurrence (n=1 / n=2).
    float* out = (float*)d_out;

    float4* pS   = (float4*)d_ws;
    float4* pQ   = pS + (size_t)RG * S4;
    float*  stats = (float*)(pQ + (size_t)RG * S4);

    // No memset: every ws byte consumed downstream is produced by stage A/B first.
    partial_kernel<<<NB1, 256, 0, stream>>>(x, pS, pQ);
    stats_kernel<<<F / 256, 256, 0, stream>>>((const float*)pS, (const float*)pQ, stats);
    normalize_kernel<<<CHUNK / 256, 256, 0, stream>>>(x, stats, out);
}